// Round 8
// baseline (200.250 us; speedup 1.0000x reference)
//
#include <hip/hip_runtime.h>

#define NEURONS 8192
#define NEURONS4 2048     // NEURONS / 4 (float4 columns)
#define BATCH_N 2048
#define GROUPF 16         // rows per load group in K1 (double-buffered float4)
#define CHUNK_ROWS 256    // batch rows per parallel chunk in K1 (8 chunks)
#define WARMUP 512        // max warmup rows (0.95^512 ~ 4e-12 -> shadowing)
#define SEG 2048          // neurons per wave in K2 (4 waves x 2048 = 8192)

// EXACT path (validated rounds 2-7, absmax 0.0): inline branch-free f64 exp,
// then numpy's f32 op sequence: ef = fl32(exp(-(f64)z)); p = fl32(1/fl32(1+ef)).
__device__ __forceinline__ float ref_sigmoid(float zf) {
    double z = -(double)zf;
    const double LOG2E  = 1.4426950408889634074;
    const double LN2_HI = 6.93147180369123816490e-01;
    const double LN2_LO = 1.90821492927058770002e-10;
    double kd = __builtin_rint(z * LOG2E);
    double r  = __builtin_fma(-kd, LN2_HI, z);
    r         = __builtin_fma(-kd, LN2_LO, r);
    double p;
    p = 2.7557319223985888e-07;                        // 1/10!
    p = __builtin_fma(p, r, 2.7557319223985893e-06);   // 1/9!
    p = __builtin_fma(p, r, 2.4801587301587302e-05);   // 1/8!
    p = __builtin_fma(p, r, 1.9841269841269841e-04);   // 1/7!
    p = __builtin_fma(p, r, 1.3888888888888889e-03);   // 1/6!
    p = __builtin_fma(p, r, 8.3333333333333332e-03);   // 1/5!
    p = __builtin_fma(p, r, 4.1666666666666664e-02);   // 1/4!
    p = __builtin_fma(p, r, 1.6666666666666666e-01);   // 1/3!
    p = __builtin_fma(p, r, 5.0e-01);                  // 1/2!
    p = __builtin_fma(p, r, 1.0);
    p = __builtin_fma(p, r, 1.0);
    long long ki = (long long)kd;
    double two_k = __longlong_as_double((unsigned long long)(ki + 1023) << 52);
    float ef = (float)(p * two_k);
    return __fdiv_rn(1.0f, __fadd_rn(1.0f, ef));
}

__device__ __forceinline__ void lif_step4(float4& v, const float4& b) {
    const float alpha = 0.05f;
    v.x = __fadd_rn(v.x, __fmul_rn(alpha, __fadd_rn(b.x, -v.x)));
    v.y = __fadd_rn(v.y, __fmul_rn(alpha, __fadd_rn(b.y, -v.y)));
    v.z = __fadd_rn(v.z, __fmul_rn(alpha, __fadd_rn(b.z, -v.z)));
    v.w = __fadd_rn(v.w, __fmul_rn(alpha, __fadd_rn(b.w, -v.w)));
}

// One span of the LIF recurrence in float4 lanes (nrows multiple of 2*GROUPF),
// double-buffered in GROUPF=16 row groups: 16 outstanding dwordx4 loads/lane
// (1 KB contiguous per wave-load -> the m13-style pattern that reaches
// ~6.3 TB/s, vs 256 B/load in the scalar version capped at ~2.8 TB/s).
// Exact f32 op order per component: v = v + alpha*(i - v), no FMA contraction.
template <bool STORE>
__device__ __forceinline__ float4 lif_span4(const float4* __restrict__ ip,
                                            float4* __restrict__ vp, float4 v,
                                            int nrows) {
    float4 buf0[GROUPF], buf1[GROUPF];
    #pragma unroll
    for (int k = 0; k < GROUPF; ++k) buf0[k] = ip[(size_t)k * NEURONS4];

    const int NGROUPS = nrows / GROUPF;   // 16 or 32, even
    for (int g = 0; g < NGROUPS; g += 2) {
        {   // prefetch group g+1
            const float4* p = ip + (size_t)(g + 1) * GROUPF * NEURONS4;
            #pragma unroll
            for (int k = 0; k < GROUPF; ++k) buf1[k] = p[(size_t)k * NEURONS4];
        }
        {   // compute group g
            float4* q = vp + (size_t)g * GROUPF * NEURONS4;
            #pragma unroll
            for (int k = 0; k < GROUPF; ++k) {
                lif_step4(v, buf0[k]);
                if constexpr (STORE) q[(size_t)k * NEURONS4] = v;
            }
        }
        if (g + 2 < NGROUPS) {   // prefetch group g+2
            const float4* p = ip + (size_t)(g + 2) * GROUPF * NEURONS4;
            #pragma unroll
            for (int k = 0; k < GROUPF; ++k) buf0[k] = p[(size_t)k * NEURONS4];
        }
        {   // compute group g+1
            float4* q = vp + (size_t)(g + 1) * GROUPF * NEURONS4;
            #pragma unroll
            for (int k = 0; k < GROUPF; ++k) {
                lif_step4(v, buf1[k]);
                if constexpr (STORE) q[(size_t)k * NEURONS4] = v;
            }
        }
    }
    return v;
}

// K1: LIF membrane recurrence, float4 lanes, batch-parallelized into 8 chunks
// of 256 rows. Chunk c warms up on the preceding min(512, 256c) rows (no
// stores) from V0: c=0 none; c=1,2 exact replay; c>=3 512-row warmup with
// initial-state influence 0.95^512 ~ 4e-12 << 1 ulp -> exact merge
// (rounding shadowing; validated absmax 0.0, rounds 4-7).
__global__ __launch_bounds__(64) void lif_v_kernel(const float4* __restrict__ I,
                                                   const float4* __restrict__ V0,
                                                   float4* __restrict__ V) {
    int nb    = blockIdx.x & 31;         // column block (32 x 64 = 2048 f4-cols)
    int chunk = blockIdx.x >> 5;         // 0..7
    int j4 = nb * 64 + (int)threadIdx.x; // float4 column
    float4 v = V0[j4];
    int row0 = chunk * CHUNK_ROWS;
    int w = (row0 < WARMUP) ? row0 : WARMUP;   // 0, 256, or 512
    if (w > 0) {
        const float4* ip = I + (size_t)(row0 - w) * NEURONS4 + j4;
        v = lif_span4<false>(ip, nullptr, v, w);
    }
    const float4* ip = I + (size_t)row0 * NEURONS4 + j4;
    float4*       vp = V + (size_t)row0 * NEURONS4 + j4;
    lif_span4<true>(ip, vp, v, CHUNK_ROWS);
}

// K2: autoregressive Bernoulli scan, one block (4 waves) per row, each wave
// owning 2048 neurons, dual carry hypotheses + f32 certificate with rare
// exact f64 fallback (validated rounds 6-7, absmax 0.0).
__global__ __launch_bounds__(256) void spike_kernel(const float* __restrict__ U,
                                                    float* __restrict__ VS) {
    __shared__ int m0s[4], m1s[4];
    int row  = blockIdx.x;
    int wid  = threadIdx.x >> 6;          // 0..3
    int lane = threadIdx.x & 63;
    const size_t rbase = (size_t)row * NEURONS;
    const float* u_seg = U  + rbase + wid * SEG;
    float*      vs_seg = VS + rbase + wid * SEG;
    const unsigned long long ltmask =
        (lane == 0) ? 0ull : (~0ull >> (64 - lane));   // lanes strictly below

    const float NLOG2E = -1.4426950408889634f;  // -log2(e)
    const float EHALF  = 0.60653065971263342f;  // e^-0.5
    const float M      = 4e-6f;                 // certificate margin

    float4 cv = *reinterpret_cast<const float4*>(vs_seg + lane * 4);
    float4 cu = *reinterpret_cast<const float4*>(u_seg + lane * 4);

    unsigned int out_a = 0, out_b = 0;    // outputs under seg-carry-in 0 / 1
    int a = 0, b = 1;                      // chunk-start states, both hyps
    #pragma unroll
    for (int c8 = 0; c8 < 8; ++c8) {
        int base  = c8 * 256 + lane * 4;
        int nbase = (c8 < 7) ? (base + 256) : base;   // clamped prefetch
        float4 nv = *reinterpret_cast<const float4*>(vs_seg + nbase);
        float4 nu = *reinterpret_cast<const float4*>(u_seg + nbase);

        float vv[4] = {cv.x, cv.y, cv.z, cv.w};
        float uu[4] = {cu.x, cu.y, cu.z, cu.w};

        int s0[4], s1[4];
        int amb = 0;
        #pragma unroll
        for (int k = 0; k < 4; ++k) {
            float t  = vv[k] * NLOG2E;                   // -v*log2e
            float e0 = __builtin_amdgcn_exp2f(t);        // ~exp(-v)
            float e1 = e0 * EHALF;                       // ~exp(-(v+0.5))
            float um1 = uu[k] - 1.0f;
            float q0 = fmaf(uu[k], e0, um1);             // u*(1+e0) - 1
            float q1 = fmaf(uu[k], e1, um1);
            s0[k] = (q0 < 0.0f) ? 1 : 0;
            s1[k] = (q1 < 0.0f) ? 1 : 0;
            amb |= (fabsf(q0) <= M) | (fabsf(q1) <= M);
        }
        if (__any(amb)) {                 // rare: exact recompute, whole wave
            #pragma unroll
            for (int k = 0; k < 4; ++k) {
                s0[k] = (uu[k] < ref_sigmoid(vv[k])) ? 1 : 0;
                s1[k] = (uu[k] < ref_sigmoid(__fadd_rn(vv[k], 0.5f))) ? 1 : 0;
            }
        }

        // per-lane composed map over 4 neurons
        int st0 = 0, st1 = 1;
        #pragma unroll
        for (int k = 0; k < 4; ++k) {
            st0 = st0 ? s1[k] : s0[k];
            st1 = st1 ? s1[k] : s0[k];
        }

        unsigned long long constMask = __ballot(st0 == st1);
        unsigned long long valMask   = __ballot(st0 != 0);
        unsigned long long below     = constMask & ltmask;
        int vb  = below ? (int)((valMask >> (63 - __clzll(below))) & 1ull) : 0;
        int has = below ? 1 : 0;
        int cin0 = has ? vb : 0;          // lane carry-in if chunk starts at 0
        int cin1 = has ? vb : 1;          // ... if chunk starts at 1

        int sA = cin0, sB = cin1;
        unsigned int o0 = 0, o1 = 0;      // lane's 4 outputs, both chunk hyps
        #pragma unroll
        for (int k = 0; k < 4; ++k) {
            sA = sA ? s1[k] : s0[k];  o0 |= (unsigned)sA << k;
            sB = sB ? s1[k] : s0[k];  o1 |= (unsigned)sB << k;
        }
        int t0 = __shfl(sA, 63);          // chunk map applied to 0
        int t1 = __shfl(sB, 63);          // chunk map applied to 1

        out_a |= (a ? o1 : o0) << (4 * c8);
        out_b |= (b ? o1 : o0) << (4 * c8);
        a = a ? t1 : t0;
        b = b ? t1 : t0;
        cv = nv; cu = nu;
    }

    if (lane == 0) { m0s[wid] = a; m1s[wid] = b; }
    __syncthreads();
    int cin = 0;                          // row starts with prev_spike = 0
    for (int i = 0; i < wid; ++i) cin = cin ? m1s[i] : m0s[i];
    unsigned int bits = cin ? out_b : out_a;

    #pragma unroll
    for (int c8 = 0; c8 < 8; ++c8) {
        unsigned int nib = bits >> (4 * c8);
        *reinterpret_cast<float4*>(vs_seg + c8 * 256 + lane * 4) =
            make_float4((float)(nib & 1), (float)((nib >> 1) & 1),
                        (float)((nib >> 2) & 1), (float)((nib >> 3) & 1));
    }
}

extern "C" void kernel_launch(void* const* d_in, const int* in_sizes, int n_in,
                              void* d_out, int out_size, void* d_ws, size_t ws_size,
                              hipStream_t stream) {
    const float4* I  = (const float4*)d_in[0];  // input_current (2048, 8192) f32
    const float*  U  = (const float*)d_in[1];   // u             (2048, 8192) f32
    const float4* V0 = (const float4*)d_in[2];  // v0            (8192,)      f32
    float* OUT = (float*)d_out;                 // spikes; also V scratch

    (void)in_sizes; (void)n_in; (void)out_size; (void)d_ws; (void)ws_size;

    // K1: 8 batch-chunks x 32 column-blocks = 256 blocks x 64 threads (float4)
    lif_v_kernel<<<256, 64, 0, stream>>>(I, V0, (float4*)OUT);
    // K2: one block (4 waves) per batch row
    spike_kernel<<<BATCH_N, 256, 0, stream>>>(U, OUT);
}

// Round 9
// 195.459 us; speedup vs baseline: 1.0245x; 1.0245x over previous
//
#include <hip/hip_runtime.h>

#define NEURONS 8192
#define NEURONS4 2048     // NEURONS / 4 (float4 columns)
#define BATCH_N 2048
#define GROUPF 16         // rows per load group in K1 (double-buffered float4)
#define CHUNK_ROWS 256    // batch rows per parallel chunk in K1 (8 chunks)
#define WARMUP 512        // max warmup rows (0.95^512 ~ 4e-12 -> shadowing)
#define SEG 2048          // neurons per wave in K2 (4 waves x 2048 = 8192)

// EXACT path (validated rounds 2-8, absmax 0.0): inline branch-free f64 exp,
// then numpy's f32 op sequence: ef = fl32(exp(-(f64)z)); p = fl32(1/fl32(1+ef)).
__device__ __forceinline__ float ref_sigmoid(float zf) {
    double z = -(double)zf;
    const double LOG2E  = 1.4426950408889634074;
    const double LN2_HI = 6.93147180369123816490e-01;
    const double LN2_LO = 1.90821492927058770002e-10;
    double kd = __builtin_rint(z * LOG2E);
    double r  = __builtin_fma(-kd, LN2_HI, z);
    r         = __builtin_fma(-kd, LN2_LO, r);
    double p;
    p = 2.7557319223985888e-07;                        // 1/10!
    p = __builtin_fma(p, r, 2.7557319223985893e-06);   // 1/9!
    p = __builtin_fma(p, r, 2.4801587301587302e-05);   // 1/8!
    p = __builtin_fma(p, r, 1.9841269841269841e-04);   // 1/7!
    p = __builtin_fma(p, r, 1.3888888888888889e-03);   // 1/6!
    p = __builtin_fma(p, r, 8.3333333333333332e-03);   // 1/5!
    p = __builtin_fma(p, r, 4.1666666666666664e-02);   // 1/4!
    p = __builtin_fma(p, r, 1.6666666666666666e-01);   // 1/3!
    p = __builtin_fma(p, r, 5.0e-01);                  // 1/2!
    p = __builtin_fma(p, r, 1.0);
    p = __builtin_fma(p, r, 1.0);
    long long ki = (long long)kd;
    double two_k = __longlong_as_double((unsigned long long)(ki + 1023) << 52);
    float ef = (float)(p * two_k);
    return __fdiv_rn(1.0f, __fadd_rn(1.0f, ef));
}

__device__ __forceinline__ void lif_step4(float4& v, const float4& b) {
    const float alpha = 0.05f;
    v.x = __fadd_rn(v.x, __fmul_rn(alpha, __fadd_rn(b.x, -v.x)));
    v.y = __fadd_rn(v.y, __fmul_rn(alpha, __fadd_rn(b.y, -v.y)));
    v.z = __fadd_rn(v.z, __fmul_rn(alpha, __fadd_rn(b.z, -v.z)));
    v.w = __fadd_rn(v.w, __fmul_rn(alpha, __fadd_rn(b.w, -v.w)));
}

// One span of the LIF recurrence in float4 lanes (nrows multiple of 2*GROUPF),
// double-buffered in GROUPF=16 row groups: 16 outstanding dwordx4 loads/lane
// (16 KB in flight per wave). Requires the full 128-VGPR double buffer to be
// register-resident -> kernel is compiled with __launch_bounds__(64, 1)
// (round 8: without the hint the compiler capped VGPR=104 and serialized the
// window -> 2.7 TB/s).
// Exact f32 op order per component: v = v + alpha*(i - v), no FMA contraction.
template <bool STORE>
__device__ __forceinline__ float4 lif_span4(const float4* __restrict__ ip,
                                            float4* __restrict__ vp, float4 v,
                                            int nrows) {
    float4 buf0[GROUPF], buf1[GROUPF];
    #pragma unroll
    for (int k = 0; k < GROUPF; ++k) buf0[k] = ip[(size_t)k * NEURONS4];

    const int NGROUPS = nrows / GROUPF;   // 16 or 32, even
    for (int g = 0; g < NGROUPS; g += 2) {
        {   // prefetch group g+1
            const float4* p = ip + (size_t)(g + 1) * GROUPF * NEURONS4;
            #pragma unroll
            for (int k = 0; k < GROUPF; ++k) buf1[k] = p[(size_t)k * NEURONS4];
        }
        {   // compute group g
            float4* q = vp + (size_t)g * GROUPF * NEURONS4;
            #pragma unroll
            for (int k = 0; k < GROUPF; ++k) {
                lif_step4(v, buf0[k]);
                if constexpr (STORE) q[(size_t)k * NEURONS4] = v;
            }
        }
        if (g + 2 < NGROUPS) {   // prefetch group g+2
            const float4* p = ip + (size_t)(g + 2) * GROUPF * NEURONS4;
            #pragma unroll
            for (int k = 0; k < GROUPF; ++k) buf0[k] = p[(size_t)k * NEURONS4];
        }
        {   // compute group g+1
            float4* q = vp + (size_t)(g + 1) * GROUPF * NEURONS4;
            #pragma unroll
            for (int k = 0; k < GROUPF; ++k) {
                lif_step4(v, buf1[k]);
                if constexpr (STORE) q[(size_t)k * NEURONS4] = v;
            }
        }
    }
    return v;
}

// K1: LIF membrane recurrence, float4 lanes, batch-parallelized into 8 chunks
// of 256 rows. Chunk c warms up on the preceding min(512, 256c) rows (no
// stores) from V0: c=0 none; c=1,2 exact replay; c>=3 512-row warmup with
// initial-state influence 0.95^512 ~ 4e-12 << 1 ulp -> exact merge
// (rounding shadowing; validated absmax 0.0, rounds 4-8).
// __launch_bounds__(64, 1): 1 wave/EU minimum -> VGPR budget up to 512, so
// the 2x16 float4 double buffer stays register-resident.
__global__ __launch_bounds__(64, 1) void lif_v_kernel(const float4* __restrict__ I,
                                                      const float4* __restrict__ V0,
                                                      float4* __restrict__ V) {
    int nb    = blockIdx.x & 31;         // column block (32 x 64 = 2048 f4-cols)
    int chunk = blockIdx.x >> 5;         // 0..7
    int j4 = nb * 64 + (int)threadIdx.x; // float4 column
    float4 v = V0[j4];
    int row0 = chunk * CHUNK_ROWS;
    int w = (row0 < WARMUP) ? row0 : WARMUP;   // 0, 256, or 512
    if (w > 0) {
        const float4* ip = I + (size_t)(row0 - w) * NEURONS4 + j4;
        v = lif_span4<false>(ip, nullptr, v, w);
    }
    const float4* ip = I + (size_t)row0 * NEURONS4 + j4;
    float4*       vp = V + (size_t)row0 * NEURONS4 + j4;
    lif_span4<true>(ip, vp, v, CHUNK_ROWS);
}

// K2: autoregressive Bernoulli scan, one block (4 waves) per row, each wave
// owning 2048 neurons, dual carry hypotheses + f32 certificate with rare
// exact f64 fallback (validated rounds 6-8, absmax 0.0).
__global__ __launch_bounds__(256) void spike_kernel(const float* __restrict__ U,
                                                    float* __restrict__ VS) {
    __shared__ int m0s[4], m1s[4];
    int row  = blockIdx.x;
    int wid  = threadIdx.x >> 6;          // 0..3
    int lane = threadIdx.x & 63;
    const size_t rbase = (size_t)row * NEURONS;
    const float* u_seg = U  + rbase + wid * SEG;
    float*      vs_seg = VS + rbase + wid * SEG;
    const unsigned long long ltmask =
        (lane == 0) ? 0ull : (~0ull >> (64 - lane));   // lanes strictly below

    const float NLOG2E = -1.4426950408889634f;  // -log2(e)
    const float EHALF  = 0.60653065971263342f;  // e^-0.5
    const float M      = 4e-6f;                 // certificate margin

    float4 cv = *reinterpret_cast<const float4*>(vs_seg + lane * 4);
    float4 cu = *reinterpret_cast<const float4*>(u_seg + lane * 4);

    unsigned int out_a = 0, out_b = 0;    // outputs under seg-carry-in 0 / 1
    int a = 0, b = 1;                      // chunk-start states, both hyps
    #pragma unroll
    for (int c8 = 0; c8 < 8; ++c8) {
        int base  = c8 * 256 + lane * 4;
        int nbase = (c8 < 7) ? (base + 256) : base;   // clamped prefetch
        float4 nv = *reinterpret_cast<const float4*>(vs_seg + nbase);
        float4 nu = *reinterpret_cast<const float4*>(u_seg + nbase);

        float vv[4] = {cv.x, cv.y, cv.z, cv.w};
        float uu[4] = {cu.x, cu.y, cu.z, cu.w};

        int s0[4], s1[4];
        int amb = 0;
        #pragma unroll
        for (int k = 0; k < 4; ++k) {
            float t  = vv[k] * NLOG2E;                   // -v*log2e
            float e0 = __builtin_amdgcn_exp2f(t);        // ~exp(-v)
            float e1 = e0 * EHALF;                       // ~exp(-(v+0.5))
            float um1 = uu[k] - 1.0f;
            float q0 = fmaf(uu[k], e0, um1);             // u*(1+e0) - 1
            float q1 = fmaf(uu[k], e1, um1);
            s0[k] = (q0 < 0.0f) ? 1 : 0;
            s1[k] = (q1 < 0.0f) ? 1 : 0;
            amb |= (fabsf(q0) <= M) | (fabsf(q1) <= M);
        }
        if (__any(amb)) {                 // rare: exact recompute, whole wave
            #pragma unroll
            for (int k = 0; k < 4; ++k) {
                s0[k] = (uu[k] < ref_sigmoid(vv[k])) ? 1 : 0;
                s1[k] = (uu[k] < ref_sigmoid(__fadd_rn(vv[k], 0.5f))) ? 1 : 0;
            }
        }

        // per-lane composed map over 4 neurons
        int st0 = 0, st1 = 1;
        #pragma unroll
        for (int k = 0; k < 4; ++k) {
            st0 = st0 ? s1[k] : s0[k];
            st1 = st1 ? s1[k] : s0[k];
        }

        unsigned long long constMask = __ballot(st0 == st1);
        unsigned long long valMask   = __ballot(st0 != 0);
        unsigned long long below     = constMask & ltmask;
        int vb  = below ? (int)((valMask >> (63 - __clzll(below))) & 1ull) : 0;
        int has = below ? 1 : 0;
        int cin0 = has ? vb : 0;          // lane carry-in if chunk starts at 0
        int cin1 = has ? vb : 1;          // ... if chunk starts at 1

        int sA = cin0, sB = cin1;
        unsigned int o0 = 0, o1 = 0;      // lane's 4 outputs, both chunk hyps
        #pragma unroll
        for (int k = 0; k < 4; ++k) {
            sA = sA ? s1[k] : s0[k];  o0 |= (unsigned)sA << k;
            sB = sB ? s1[k] : s0[k];  o1 |= (unsigned)sB << k;
        }
        int t0 = __shfl(sA, 63);          // chunk map applied to 0
        int t1 = __shfl(sB, 63);          // chunk map applied to 1

        out_a |= (a ? o1 : o0) << (4 * c8);
        out_b |= (b ? o1 : o0) << (4 * c8);
        a = a ? t1 : t0;
        b = b ? t1 : t0;
        cv = nv; cu = nu;
    }

    if (lane == 0) { m0s[wid] = a; m1s[wid] = b; }
    __syncthreads();
    int cin = 0;                          // row starts with prev_spike = 0
    for (int i = 0; i < wid; ++i) cin = cin ? m1s[i] : m0s[i];
    unsigned int bits = cin ? out_b : out_a;

    #pragma unroll
    for (int c8 = 0; c8 < 8; ++c8) {
        unsigned int nib = bits >> (4 * c8);
        *reinterpret_cast<float4*>(vs_seg + c8 * 256 + lane * 4) =
            make_float4((float)(nib & 1), (float)((nib >> 1) & 1),
                        (float)((nib >> 2) & 1), (float)((nib >> 3) & 1));
    }
}

extern "C" void kernel_launch(void* const* d_in, const int* in_sizes, int n_in,
                              void* d_out, int out_size, void* d_ws, size_t ws_size,
                              hipStream_t stream) {
    const float4* I  = (const float4*)d_in[0];  // input_current (2048, 8192) f32
    const float*  U  = (const float*)d_in[1];   // u             (2048, 8192) f32
    const float4* V0 = (const float4*)d_in[2];  // v0            (8192,)      f32
    float* OUT = (float*)d_out;                 // spikes; also V scratch

    (void)in_sizes; (void)n_in; (void)out_size; (void)d_ws; (void)ws_size;

    // K1: 8 batch-chunks x 32 column-blocks = 256 blocks x 64 threads (float4)
    lif_v_kernel<<<256, 64, 0, stream>>>(I, V0, (float4*)OUT);
    // K2: one block (4 waves) per batch row
    spike_kernel<<<BATCH_N, 256, 0, stream>>>(U, OUT);
}